// Round 2
// baseline (1742.258 us; speedup 1.0000x reference)
//
#include <hip/hip_runtime.h>
#include <hip/hip_bf16.h>

static __device__ __forceinline__ float lrelu01(float v) { return v > 0.0f ? v : 0.01f * v; }

// ---------------- K_proj: 5 feature projections -> h0[N][160] ----------------
// grid = (ceil(n/256), 5); seg: 0=num_prop(6) 1=num_cat(11) 2=des(768) 3=tweet(768) 4=pre_x(768)
__global__ __launch_bounds__(256) void k_proj(
    const float* __restrict__ pre_x,
    const float* __restrict__ num_prop,
    const float* __restrict__ num_cat,
    const float* __restrict__ des,
    const float* __restrict__ tweet,
    const float* __restrict__ w_np, const float* __restrict__ b_np,
    const float* __restrict__ w_nc, const float* __restrict__ b_nc,
    const float* __restrict__ w_des, const float* __restrict__ b_des,
    const float* __restrict__ w_text, const float* __restrict__ b_text,
    const float* __restrict__ w_tw, const float* __restrict__ b_tw,
    float* __restrict__ h0, int n)
{
  const int node = blockIdx.x * 256 + threadIdx.x;
  if (node >= n) return;
  const int seg = blockIdx.y;

  const float* x; const float* w; const float* b; int din;
  switch (seg) {
    case 0:  x = num_prop; w = w_np;   b = b_np;   din = 6;   break;
    case 1:  x = num_cat;  w = w_nc;   b = b_nc;   din = 11;  break;
    case 2:  x = des;      w = w_des;  b = b_des;  din = 768; break;
    case 3:  x = tweet;    w = w_text; b = b_text; din = 768; break;
    default: x = pre_x;    w = w_tw;   b = b_tw;   din = 768; break;
  }

  float acc[32];
  #pragma unroll
  for (int c = 0; c < 32; ++c) acc[c] = 0.0f;

  if (din == 768) {
    const float4* xr = reinterpret_cast<const float4*>(x + (size_t)node * 768);
    for (int kb = 0; kb < 192; ++kb) {
      const float4 xv = xr[kb];
      #pragma unroll
      for (int c = 0; c < 32; ++c) {
        // wave-uniform address -> scalar loads through constant cache
        const float4 wv = *reinterpret_cast<const float4*>(w + c * 768 + kb * 4);
        acc[c] = fmaf(xv.x, wv.x, acc[c]);
        acc[c] = fmaf(xv.y, wv.y, acc[c]);
        acc[c] = fmaf(xv.z, wv.z, acc[c]);
        acc[c] = fmaf(xv.w, wv.w, acc[c]);
      }
    }
  } else {
    const float* xr = x + (size_t)node * din;
    for (int k = 0; k < din; ++k) {
      const float xv = xr[k];
      #pragma unroll
      for (int c = 0; c < 32; ++c) acc[c] = fmaf(xv, w[c * din + k], acc[c]);
    }
  }

  float* out = h0 + (size_t)node * 160 + seg * 32;
  #pragma unroll
  for (int c = 0; c < 32; ++c) out[c] = lrelu01(acc[c] + b[c]);
}

// ---------------- generic [n,160] x [dout,160]^T, 32-col segment per blockIdx.y ----------------
__global__ __launch_bounds__(256) void k_lin160(
    const float* __restrict__ x, const float* __restrict__ w,
    const float* __restrict__ bias, float* __restrict__ out,
    int n, int act)
{
  const int node = blockIdx.x * 256 + threadIdx.x;
  if (node >= n) return;
  const int seg = blockIdx.y;
  const float4* xr = reinterpret_cast<const float4*>(x + (size_t)node * 160);

  float acc[32];
  #pragma unroll
  for (int c = 0; c < 32; ++c) acc[c] = 0.0f;

  for (int k4 = 0; k4 < 40; ++k4) {
    const float4 xv = xr[k4];
    #pragma unroll
    for (int c = 0; c < 32; ++c) {
      const float4 wv = *reinterpret_cast<const float4*>(w + (size_t)(seg * 32 + c) * 160 + k4 * 4);
      acc[c] = fmaf(xv.x, wv.x, acc[c]);
      acc[c] = fmaf(xv.y, wv.y, acc[c]);
      acc[c] = fmaf(xv.z, wv.z, acc[c]);
      acc[c] = fmaf(xv.w, wv.w, acc[c]);
    }
  }

  float* o = out + (size_t)node * 160 + seg * 32;
  #pragma unroll
  for (int c = 0; c < 32; ++c) {
    float v = acc[c] + (bias ? bias[seg * 32 + c] : 0.0f);
    if (act) v = lrelu01(v);
    o[c] = v;
  }
}

// ---------------- per-node attention dots: a_s = <h, att_src>, a_d = <h, att_dst> ----------------
__global__ __launch_bounds__(256) void k_att(
    const float* __restrict__ h, const float* __restrict__ att_s,
    const float* __restrict__ att_d,
    float* __restrict__ a_s, float* __restrict__ a_d, int n)
{
  const int node = blockIdx.x * 256 + threadIdx.x;
  if (node >= n) return;
  const float4* r = reinterpret_cast<const float4*>(h + (size_t)node * 160);
  float s = 0.0f, d = 0.0f;
  #pragma unroll
  for (int k4 = 0; k4 < 40; ++k4) {
    const float4 v = r[k4];
    const float4 av = reinterpret_cast<const float4*>(att_s)[k4];
    const float4 dv = reinterpret_cast<const float4*>(att_d)[k4];
    s = fmaf(v.x, av.x, fmaf(v.y, av.y, fmaf(v.z, av.z, fmaf(v.w, av.w, s))));
    d = fmaf(v.x, dv.x, fmaf(v.y, dv.y, fmaf(v.z, dv.z, fmaf(v.w, dv.w, d))));
  }
  a_s[node] = s;
  a_d[node] = d;
}

// ---------------- CSR build (graph is static; built once per launch, reused both layers) ----
__global__ __launch_bounds__(256) void k_initdeg(int* __restrict__ deg, int n)
{
  const int i = blockIdx.x * 256 + threadIdx.x;
  if (i < n) deg[i] = 1;   // self-loop
}

__global__ __launch_bounds__(256) void k_count(
    const int* __restrict__ ei, int e, int* __restrict__ deg)
{
  const int i = blockIdx.x * 256 + threadIdx.x;
  if (i < e) atomicAdd(deg + ei[e + i], 1);   // dst row of edge_index
}

// single-block exclusive scan of deg[0..n) -> row_start[0..n], cursor copy
__global__ __launch_bounds__(256) void k_scan(
    const int* __restrict__ deg, int* __restrict__ row_start,
    int* __restrict__ cursor, int n)
{
  __shared__ int part[256];
  const int t = threadIdx.x;
  const int chunk = (n + 255) / 256;
  const int lo = t * chunk;
  const int hi = min(lo + chunk, n);
  int s = 0;
  for (int i = lo; i < hi; ++i) s += deg[i];
  part[t] = s;
  __syncthreads();
  for (int off = 1; off < 256; off <<= 1) {
    int v = (t >= off) ? part[t - off] : 0;
    __syncthreads();
    part[t] += v;
    __syncthreads();
  }
  int base = (t == 0) ? 0 : part[t - 1];
  for (int i = lo; i < hi; ++i) {
    row_start[i] = base;
    cursor[i] = base;
    base += deg[i];
  }
  if (t == 0) row_start[n] = part[255];
}

// scatter edge list into CSR slots; [0,E) real edges, [E,E+N) self-loops
__global__ __launch_bounds__(256) void k_scatter(
    const int* __restrict__ ei, int e, int n,
    int* __restrict__ cursor, int* __restrict__ csr_src)
{
  const int i = blockIdx.x * 256 + threadIdx.x;
  const int total = e + n;
  if (i >= total) return;
  int s, d;
  if (i < e) { s = ei[i]; d = ei[e + i]; }
  else       { s = i - e; d = s; }
  const int slot = atomicAdd(cursor + d, 1);
  csr_src[slot] = s;
}

// ---------------- gather: one 64-lane wave per destination node ----------------
// out[d] = (sum_e ex_e * h[src_e]) / (sum_e ex_e + 1e-16) + bias     (fuses softmax+aggregate+norm)
__global__ __launch_bounds__(256) void k_gather(
    const int* __restrict__ row_start, const int* __restrict__ csr_src,
    const float* __restrict__ h, const float* __restrict__ a_s,
    const float* __restrict__ a_d, const float* __restrict__ bias,
    float* __restrict__ out, int n)
{
  const int d = blockIdx.x * 4 + (threadIdx.x >> 6);
  if (d >= n) return;                       // wave-uniform branch
  const int lane = threadIdx.x & 63;
  const int beg = row_start[d];
  const int end = row_start[d + 1];
  const float ad = a_d[d];

  float z = 0.0f, acc0 = 0.0f, acc1 = 0.0f, acc2 = 0.0f;
  const bool has2 = lane < 32;              // channels 128..159

  for (int s = beg; s < end; ++s) {
    const int src = csr_src[s];             // broadcast load
    float e = a_s[src] + ad;                // broadcast load
    e = e > 0.0f ? e : 0.2f * e;            // negative_slope = 0.2
    const float ex = expf(e);               // shift-invariant: skip segment_max
    z += ex;
    const float* hr = h + (size_t)src * 160;
    acc0 = fmaf(ex, hr[lane], acc0);
    acc1 = fmaf(ex, hr[lane + 64], acc1);
    if (has2) acc2 = fmaf(ex, hr[lane + 128], acc2);
  }

  const float inv = 1.0f / (z + 1e-16f);
  float* o = out + (size_t)d * 160;
  o[lane]      = fmaf(acc0, inv, bias[lane]);
  o[lane + 64] = fmaf(acc1, inv, bias[lane + 64]);
  if (has2) o[lane + 128] = fmaf(acc2, inv, bias[lane + 128]);
}

// ---------------- head: em = lrelu(h @ w_o1^T + b_o1); out = em @ w_o2^T + b_o2 ----------------
__global__ __launch_bounds__(256) void k_out(
    const float* __restrict__ h,
    const float* __restrict__ w1, const float* __restrict__ b1,
    const float* __restrict__ w2, const float* __restrict__ b2,
    float* __restrict__ out2, float* __restrict__ em, int n)
{
  const int node = blockIdx.x * 256 + threadIdx.x;
  if (node >= n) return;
  const float4* xr = reinterpret_cast<const float4*>(h + (size_t)node * 160);

  float acc[80];
  #pragma unroll
  for (int c = 0; c < 80; ++c) acc[c] = 0.0f;

  for (int k4 = 0; k4 < 40; ++k4) {
    const float4 xv = xr[k4];
    #pragma unroll
    for (int c = 0; c < 80; ++c) {
      const float4 wv = *reinterpret_cast<const float4*>(w1 + (size_t)c * 160 + k4 * 4);
      acc[c] = fmaf(xv.x, wv.x, acc[c]);
      acc[c] = fmaf(xv.y, wv.y, acc[c]);
      acc[c] = fmaf(xv.z, wv.z, acc[c]);
      acc[c] = fmaf(xv.w, wv.w, acc[c]);
    }
  }

  float o0 = b2[0], o1 = b2[1];
  float* emr = em + (size_t)node * 80;
  #pragma unroll
  for (int c4 = 0; c4 < 20; ++c4) {
    float4 v;
    v.x = lrelu01(acc[c4 * 4 + 0] + b1[c4 * 4 + 0]);
    v.y = lrelu01(acc[c4 * 4 + 1] + b1[c4 * 4 + 1]);
    v.z = lrelu01(acc[c4 * 4 + 2] + b1[c4 * 4 + 2]);
    v.w = lrelu01(acc[c4 * 4 + 3] + b1[c4 * 4 + 3]);
    *reinterpret_cast<float4*>(emr + c4 * 4) = v;
    o0 = fmaf(v.x, w2[c4 * 4 + 0], fmaf(v.y, w2[c4 * 4 + 1],
         fmaf(v.z, w2[c4 * 4 + 2], fmaf(v.w, w2[c4 * 4 + 3], o0))));
    o1 = fmaf(v.x, w2[80 + c4 * 4 + 0], fmaf(v.y, w2[80 + c4 * 4 + 1],
         fmaf(v.z, w2[80 + c4 * 4 + 2], fmaf(v.w, w2[80 + c4 * 4 + 3], o1))));
  }
  out2[(size_t)node * 2 + 0] = o0;
  out2[(size_t)node * 2 + 1] = o1;
}

extern "C" void kernel_launch(void* const* d_in, const int* in_sizes, int n_in,
                              void* d_out, int out_size, void* d_ws, size_t ws_size,
                              hipStream_t stream)
{
  const float* pre_x    = (const float*)d_in[0];
  // d_in[1] = x  (unused by the reference forward)
  const float* num_prop = (const float*)d_in[2];
  const float* num_cat  = (const float*)d_in[3];
  const float* des      = (const float*)d_in[4];
  const float* tweet    = (const float*)d_in[5];
  const int*   ei       = (const int*)d_in[6];
  // d_in[7] = edge_type (unused)
  const float* w_np  = (const float*)d_in[8];  const float* b_np  = (const float*)d_in[9];
  const float* w_nc  = (const float*)d_in[10]; const float* b_nc  = (const float*)d_in[11];
  const float* w_des = (const float*)d_in[12]; const float* b_des = (const float*)d_in[13];
  const float* w_text= (const float*)d_in[14]; const float* b_text= (const float*)d_in[15];
  const float* w_tw  = (const float*)d_in[16]; const float* b_tw  = (const float*)d_in[17];
  const float* w_in  = (const float*)d_in[18]; const float* b_in  = (const float*)d_in[19];
  const float* W1    = (const float*)d_in[20]; const float* b1    = (const float*)d_in[21];
  const float* as1   = (const float*)d_in[22]; const float* ad1   = (const float*)d_in[23];
  const float* W2    = (const float*)d_in[24]; const float* b2    = (const float*)d_in[25];
  const float* as2   = (const float*)d_in[26]; const float* ad2   = (const float*)d_in[27];
  const float* w_o1  = (const float*)d_in[28]; const float* b_o1  = (const float*)d_in[29];
  const float* w_o2  = (const float*)d_in[30]; const float* b_o2  = (const float*)d_in[31];

  const int n = in_sizes[2] / 6;     // num_prop is [N,6]
  const int e = in_sizes[7];         // edge_type is [E]

  // ---- workspace carve-up (all re-poisoned each call; everything below is fully rewritten) ----
  float* buf0 = (float*)d_ws;                       // N*160
  float* buf1 = buf0 + (size_t)n * 160;             // N*160
  float* asb  = buf1 + (size_t)n * 160;             // N
  float* adb  = asb + n;                            // N
  int*   deg       = (int*)(adb + n);               // N
  int*   row_start = deg + n;                       // N+1
  int*   cursor    = row_start + (n + 1);           // N
  int*   csr_src   = cursor + n;                    // E+N

  const int nb = (n + 255) / 256;
  const int eb = (e + 255) / 256;
  const int tb = (e + n + 255) / 256;
  const int gb = (n + 3) / 4;                       // 4 waves/block, 1 dst/wave

  // ---- CSR build (once; graph shared by both GAT layers) ----
  k_initdeg<<<nb, 256, 0, stream>>>(deg, n);
  k_count<<<eb, 256, 0, stream>>>(ei, e, deg);
  k_scan<<<1, 256, 0, stream>>>(deg, row_start, cursor, n);
  k_scatter<<<tb, 256, 0, stream>>>(ei, e, n, cursor, csr_src);

  // ---- features -> h0 (buf0) -> input linear -> hA (buf1) ----
  k_proj<<<dim3(nb, 5), 256, 0, stream>>>(pre_x, num_prop, num_cat, des, tweet,
      w_np, b_np, w_nc, b_nc, w_des, b_des, w_text, b_text, w_tw, b_tw, buf0, n);
  k_lin160<<<dim3(nb, 5), 256, 0, stream>>>(buf0, w_in, b_in, buf1, n, 1);

  // ---- GAT layer 1: buf1 -> Wh (buf0) -> gather -> buf1 ----
  k_lin160<<<dim3(nb, 5), 256, 0, stream>>>(buf1, W1, nullptr, buf0, n, 0);
  k_att<<<nb, 256, 0, stream>>>(buf0, as1, ad1, asb, adb, n);
  k_gather<<<gb, 256, 0, stream>>>(row_start, csr_src, buf0, asb, adb, b1, buf1, n);

  // ---- GAT layer 2: buf1 -> Wh (buf0) -> gather -> buf1 ----
  k_lin160<<<dim3(nb, 5), 256, 0, stream>>>(buf1, W2, nullptr, buf0, n, 0);
  k_att<<<nb, 256, 0, stream>>>(buf0, as2, ad2, asb, adb, n);
  k_gather<<<gb, 256, 0, stream>>>(row_start, csr_src, buf0, asb, adb, b2, buf1, n);

  // ---- head ----
  float* out2 = (float*)d_out;
  float* em   = out2 + (size_t)n * 2;
  k_out<<<nb, 256, 0, stream>>>(buf1, w_o1, b_o1, w_o2, b_o2, out2, em, n);
}